// Round 3
// baseline (1374.105 us; speedup 1.0000x reference)
//
#include <hip/hip_runtime.h>
#include <math.h>
#include <stdint.h>

#define NROWS 4096
#define NC    50257
#define BS    256
#define NVA   1024    // phase-A float4-count (head + 4096 elements)
#define CAP   2048    // LDS candidate capacity (expected ~56/row; 2048 is ~38 sigma)

typedef float f32x4 __attribute__((ext_vector_type(4)));

// Branchless compare-swap insertion into sorted-descending top-5 (t0>=t1>=...>=t4).
__device__ __forceinline__ void insert5(float& t0, float& t1, float& t2, float& t3, float& t4, float v) {
    if (v > t4) {
        t4 = v;
        float hi;
        hi = fmaxf(t3, t4); t4 = fminf(t3, t4); t3 = hi;
        hi = fmaxf(t2, t3); t3 = fminf(t2, t3); t2 = hi;
        hi = fmaxf(t1, t2); t2 = fminf(t1, t2); t1 = hi;
        hi = fmaxf(t0, t1); t1 = fminf(t0, t1); t0 = hi;
    }
}

// Merge two sorted-descending 5-lists -> sorted-descending top-5 of the union (multiset).
// c_i = max(a_i, b_i, max_{j+k=i-1} min(a_j, b_k)). Fully branchless, register-only.
__device__ __forceinline__ void merge5(float& a0, float& a1, float& a2, float& a3, float& a4,
                                       float b0, float b1, float b2, float b3, float b4) {
    float c0 = fmaxf(a0, b0);
    float c1 = fmaxf(fmaxf(a1, b1), fminf(a0, b0));
    float c2 = fmaxf(fmaxf(a2, b2), fmaxf(fminf(a0, b1), fminf(a1, b0)));
    float c3 = fmaxf(fmaxf(a3, b3), fmaxf(fmaxf(fminf(a0, b2), fminf(a1, b1)), fminf(a2, b0)));
    float c4 = fmaxf(fmaxf(a4, b4),
                     fmaxf(fmaxf(fminf(a0, b3), fminf(a1, b2)),
                           fmaxf(fminf(a2, b1), fminf(a3, b0))));
    a0 = c0; a1 = c1; a2 = c2; a3 = c3; a4 = c4;
}

__device__ __forceinline__ void insert5x4(float& t0, float& t1, float& t2, float& t3, float& t4, f32x4 v) {
    insert5(t0, t1, t2, t3, t4, v.x);
    insert5(t0, t1, t2, t3, t4, v.y);
    insert5(t0, t1, t2, t3, t4, v.z);
    insert5(t0, t1, t2, t3, t4, v.w);
}

// Block-wide top-5 reduce; result broadcast to res5[0..4] for ALL threads.
// Must be called uniformly by all 256 threads.
__device__ __forceinline__ void block_top5(float t0, float t1, float t2, float t3, float t4,
                                           float (*red)[5], float* res5, int tid) {
    #pragma unroll
    for (int off = 1; off < 64; off <<= 1) {
        float b0 = __shfl_xor(t0, off);
        float b1 = __shfl_xor(t1, off);
        float b2 = __shfl_xor(t2, off);
        float b3 = __shfl_xor(t3, off);
        float b4 = __shfl_xor(t4, off);
        merge5(t0, t1, t2, t3, t4, b0, b1, b2, b3, b4);
    }
    const int wid = tid >> 6;
    const int lane = tid & 63;
    __syncthreads();               // protect red/res5 reuse across calls
    if (lane == 0) {
        red[wid][0] = t0; red[wid][1] = t1; red[wid][2] = t2; red[wid][3] = t3; red[wid][4] = t4;
    }
    __syncthreads();
    if (tid == 0) {
        float a0 = red[0][0], a1 = red[0][1], a2 = red[0][2], a3 = red[0][3], a4 = red[0][4];
        #pragma unroll
        for (int w = 1; w < 4; ++w)
            merge5(a0, a1, a2, a3, a4, red[w][0], red[w][1], red[w][2], red[w][3], red[w][4]);
        res5[0] = a0; res5[1] = a1; res5[2] = a2; res5[3] = a3; res5[4] = a4;
    }
    __syncthreads();
}

__global__ __launch_bounds__(BS) void topk5_thresh_kernel(const float* __restrict__ x,
                                                          float* __restrict__ out) {
    __shared__ float red[4][5];
    __shared__ float s5a[5];       // block top-5 of phase A
    __shared__ float s5c[5];       // block top-5 of candidates (or fallback full row)
    __shared__ int   s_cnt;
    __shared__ int   s_idx[CAP];
    __shared__ float s_val[CAP];

    const int row = blockIdx.x;
    const int tid = threadIdx.x;
    const size_t base = (size_t)row * (size_t)NC;
    const float* xr = x + base;
    float* outr = out + base;

    // Row starts at element row*50257 (50257 % 4 == 1) -> 16B alignment varies per row.
    const int head = (int)((4u - ((unsigned)base & 3u)) & 3u);
    const int nvec = (NC - head) >> 2;
    const int tail = head + (nvec << 2);
    const f32x4* xv = (const f32x4*)(xr + head);
    f32x4* ov = (f32x4*)(outr + head);

    if (tid == 0) s_cnt = 0;

    // ---- Phase A: top-5 of first (head + 4096) elements ----
    float t0 = -INFINITY, t1 = -INFINITY, t2 = -INFINITY, t3 = -INFINITY, t4 = -INFINITY;
    if (tid < head) insert5(t0, t1, t2, t3, t4, xr[tid]);
    #pragma unroll
    for (int i = tid; i < NVA; i += BS) {
        f32x4 a = xv[i];
        insert5x4(t0, t1, t2, t3, t4, a);
    }
    block_top5(t0, t1, t2, t3, t4, red, s5a, tid);   // also syncs s_cnt init
    const float th0 = s5a[4];      // provable lower bound on the final threshold

    // ---- Phase B: stream rest, write zeros, collect rare candidates ----
    const f32x4 z4 = {0.0f, 0.0f, 0.0f, 0.0f};
    #pragma unroll 2
    for (int i = NVA + tid; i < nvec; i += BS) {
        f32x4 a = __builtin_nontemporal_load(&xv[i]);
        __builtin_nontemporal_store(z4, &ov[i]);
        float m = fmaxf(fmaxf(a.x, a.y), fmaxf(a.z, a.w));
        if (m >= th0) {
            const int eb = head + (i << 2);
            if (a.x >= th0) { int s = atomicAdd(&s_cnt, 1); if (s < CAP) { s_idx[s] = eb;     s_val[s] = a.x; } }
            if (a.y >= th0) { int s = atomicAdd(&s_cnt, 1); if (s < CAP) { s_idx[s] = eb + 1; s_val[s] = a.y; } }
            if (a.z >= th0) { int s = atomicAdd(&s_cnt, 1); if (s < CAP) { s_idx[s] = eb + 2; s_val[s] = a.z; } }
            if (a.w >= th0) { int s = atomicAdd(&s_cnt, 1); if (s < CAP) { s_idx[s] = eb + 3; s_val[s] = a.w; } }
        }
    }
    for (int s = tail + tid; s < NC; s += BS) {      // odd remainder scalars
        float v = xr[s];
        outr[s] = 0.0f;
        if (v >= th0) { int sl = atomicAdd(&s_cnt, 1); if (sl < CAP) { s_idx[sl] = s; s_val[sl] = v; } }
    }
    __syncthreads();

    const int cnt_raw = s_cnt;
    const int cnt = cnt_raw < CAP ? cnt_raw : CAP;
    const bool ovf = cnt_raw > CAP;

    if (!ovf) {
        // ---- Final threshold = top-5 of (phase-A top-5  U  candidates) ----
        float c0 = -INFINITY, c1 = -INFINITY, c2 = -INFINITY, c3 = -INFINITY, c4 = -INFINITY;
        for (int i = tid; i < cnt; i += BS) insert5(c0, c1, c2, c3, c4, s_val[i]);
        block_top5(c0, c1, c2, c3, c4, red, s5c, tid);
        float m0 = s5c[0], m1 = s5c[1], m2 = s5c[2], m3 = s5c[3], m4 = s5c[4];
        merge5(m0, m1, m2, m3, m4, s5a[0], s5a[1], s5a[2], s5a[3], s5a[4]);
        const float th = m4;

        // ---- Fixup A: re-read first chunk (hot in cache), select, write ----
        if (tid < head) { float v = xr[tid]; outr[tid] = v >= th ? v : 0.0f; }
        #pragma unroll
        for (int i = tid; i < NVA; i += BS) {
            f32x4 a = xv[i];
            f32x4 o;
            o.x = a.x >= th ? a.x : 0.0f;
            o.y = a.y >= th ? a.y : 0.0f;
            o.z = a.z >= th ? a.z : 0.0f;
            o.w = a.w >= th ? a.w : 0.0f;
            ov[i] = o;
        }
        // ---- Fixup candidates ----
        for (int i = tid; i < cnt; i += BS) {
            if (s_val[i] >= th) outr[s_idx[i]] = s_val[i];
        }
    } else {
        // ---- Fallback (unreachable for random data): exact 2-pass recompute ----
        float f0 = -INFINITY, f1 = -INFINITY, f2 = -INFINITY, f3 = -INFINITY, f4 = -INFINITY;
        if (tid < head) insert5(f0, f1, f2, f3, f4, xr[tid]);
        for (int i = tid; i < nvec; i += BS) {
            f32x4 a = xv[i];
            insert5x4(f0, f1, f2, f3, f4, a);
        }
        for (int s = tail + tid; s < NC; s += BS) insert5(f0, f1, f2, f3, f4, xr[s]);
        block_top5(f0, f1, f2, f3, f4, red, s5c, tid);
        const float th = s5c[4];
        if (tid < head) { float v = xr[tid]; outr[tid] = v >= th ? v : 0.0f; }
        for (int i = tid; i < nvec; i += BS) {
            f32x4 a = xv[i];
            f32x4 o;
            o.x = a.x >= th ? a.x : 0.0f;
            o.y = a.y >= th ? a.y : 0.0f;
            o.z = a.z >= th ? a.z : 0.0f;
            o.w = a.w >= th ? a.w : 0.0f;
            ov[i] = o;
        }
        for (int s = tail + tid; s < NC; s += BS) {
            float v = xr[s];
            outr[s] = v >= th ? v : 0.0f;
        }
    }
}

extern "C" void kernel_launch(void* const* d_in, const int* in_sizes, int n_in,
                              void* d_out, int out_size, void* d_ws, size_t ws_size,
                              hipStream_t stream) {
    (void)in_sizes; (void)n_in; (void)d_ws; (void)ws_size; (void)out_size;
    const float* x = (const float*)d_in[0];
    float* out = (float*)d_out;
    // k is fixed at 5 by the reference setup (d_in[1] holds it); kernel is specialized.
    topk5_thresh_kernel<<<NROWS, BS, 0, stream>>>(x, out);
}

// Round 5
// 1314.906 us; speedup vs baseline: 1.0450x; 1.0450x over previous
//
#include <hip/hip_runtime.h>
#include <math.h>
#include <stdint.h>

#define NROWS 4096
#define NC    50257
#define BS    256
#define NQA   4         // prefix f32x4 per thread (held in registers)
#define NVA   (NQA*BS)  // phase-A f32x4 count = 1024 (head + 4096 elements)
#define CAP   2048      // LDS candidate capacity (expected ~56/row)

typedef float f32x4 __attribute__((ext_vector_type(4)));

// Branchless compare-swap insertion into sorted-descending top-5 (t0>=t1>=...>=t4).
__device__ __forceinline__ void insert5(float& t0, float& t1, float& t2, float& t3, float& t4, float v) {
    if (v > t4) {
        t4 = v;
        float hi;
        hi = fmaxf(t3, t4); t4 = fminf(t3, t4); t3 = hi;
        hi = fmaxf(t2, t3); t3 = fminf(t2, t3); t2 = hi;
        hi = fmaxf(t1, t2); t2 = fminf(t1, t2); t1 = hi;
        hi = fmaxf(t0, t1); t1 = fminf(t0, t1); t0 = hi;
    }
}

// Merge two sorted-descending 5-lists -> sorted-descending top-5 of the union.
// c_i = max(a_i, b_i, max_{j+k=i-1} min(a_j, b_k)). Fully branchless, register-only.
__device__ __forceinline__ void merge5(float& a0, float& a1, float& a2, float& a3, float& a4,
                                       float b0, float b1, float b2, float b3, float b4) {
    float c0 = fmaxf(a0, b0);
    float c1 = fmaxf(fmaxf(a1, b1), fminf(a0, b0));
    float c2 = fmaxf(fmaxf(a2, b2), fmaxf(fminf(a0, b1), fminf(a1, b0)));
    float c3 = fmaxf(fmaxf(a3, b3), fmaxf(fmaxf(fminf(a0, b2), fminf(a1, b1)), fminf(a2, b0)));
    float c4 = fmaxf(fmaxf(a4, b4),
                     fmaxf(fmaxf(fminf(a0, b3), fminf(a1, b2)),
                           fmaxf(fminf(a2, b1), fminf(a3, b0))));
    a0 = c0; a1 = c1; a2 = c2; a3 = c3; a4 = c4;
}

__device__ __forceinline__ void insert5x4(float& t0, float& t1, float& t2, float& t3, float& t4, f32x4 v) {
    insert5(t0, t1, t2, t3, t4, v.x);
    insert5(t0, t1, t2, t3, t4, v.y);
    insert5(t0, t1, t2, t3, t4, v.z);
    insert5(t0, t1, t2, t3, t4, v.w);
}

// Block-wide top-5 reduce; result broadcast to res5[0..4]. Call uniformly (all 256 threads).
__device__ __forceinline__ void block_top5(float t0, float t1, float t2, float t3, float t4,
                                           float (*red)[5], float* res5, int tid) {
    #pragma unroll
    for (int off = 1; off < 64; off <<= 1) {
        float b0 = __shfl_xor(t0, off);
        float b1 = __shfl_xor(t1, off);
        float b2 = __shfl_xor(t2, off);
        float b3 = __shfl_xor(t3, off);
        float b4 = __shfl_xor(t4, off);
        merge5(t0, t1, t2, t3, t4, b0, b1, b2, b3, b4);
    }
    const int wid = tid >> 6;
    const int lane = tid & 63;
    __syncthreads();               // protect red/res5 reuse across calls
    if (lane == 0) {
        red[wid][0] = t0; red[wid][1] = t1; red[wid][2] = t2; red[wid][3] = t3; red[wid][4] = t4;
    }
    __syncthreads();
    if (tid == 0) {
        float a0 = red[0][0], a1 = red[0][1], a2 = red[0][2], a3 = red[0][3], a4 = red[0][4];
        #pragma unroll
        for (int w = 1; w < 4; ++w)
            merge5(a0, a1, a2, a3, a4, red[w][0], red[w][1], red[w][2], red[w][3], red[w][4]);
        res5[0] = a0; res5[1] = a1; res5[2] = a2; res5[3] = a3; res5[4] = a4;
    }
    __syncthreads();
}

// Test 4 elements of one f32x4 against th0; bank survivors in LDS.
__device__ __forceinline__ void scan4(f32x4 a, int eb, float th0,
                                      int* s_cnt, int* s_idx, float* s_val) {
    float m = fmaxf(fmaxf(a.x, a.y), fmaxf(a.z, a.w));
    if (__builtin_expect(m >= th0, 0)) {
        if (a.x >= th0) { int s = atomicAdd(s_cnt, 1); if (s < CAP) { s_idx[s] = eb;     s_val[s] = a.x; } }
        if (a.y >= th0) { int s = atomicAdd(s_cnt, 1); if (s < CAP) { s_idx[s] = eb + 1; s_val[s] = a.y; } }
        if (a.z >= th0) { int s = atomicAdd(s_cnt, 1); if (s < CAP) { s_idx[s] = eb + 2; s_val[s] = a.z; } }
        if (a.w >= th0) { int s = atomicAdd(s_cnt, 1); if (s < CAP) { s_idx[s] = eb + 3; s_val[s] = a.w; } }
    }
}

__global__ __launch_bounds__(BS) void topk5_thresh_kernel(const float* __restrict__ x,
                                                          float* __restrict__ out) {
    __shared__ float red[4][5];
    __shared__ float s5a[5];       // block top-5 of phase A
    __shared__ float s5c[5];       // block top-5 of candidates (or fallback full row)
    __shared__ int   s_cnt;
    __shared__ int   s_idx[CAP];
    __shared__ float s_val[CAP];

    const int row = blockIdx.x;
    const int tid = threadIdx.x;
    const size_t base = (size_t)row * (size_t)NC;
    const float* xr = x + base;
    float* outr = out + base;

    // Row starts at element row*50257 (50257 % 4 == 1) -> 16B alignment varies per row.
    const int head = (int)((4u - ((unsigned)base & 3u)) & 3u);
    const int nvec = (NC - head) >> 2;
    const int tail = head + (nvec << 2);
    const f32x4* xv = (const f32x4*)(xr + head);
    f32x4* ov = (f32x4*)(outr + head);

    if (tid == 0) s_cnt = 0;

    // ---- Phase A: prefix (head + 4096 elems) -> REGISTERS, compute top-5 ----
    const bool hhas = tid < head;
    float hv = 0.0f;
    if (hhas) hv = xr[tid];
    f32x4 pa[NQA];
    #pragma unroll
    for (int q = 0; q < NQA; ++q) pa[q] = xv[tid + q * BS];   // static indices -> stays in VGPRs

    float t0 = -INFINITY, t1 = -INFINITY, t2 = -INFINITY, t3 = -INFINITY, t4 = -INFINITY;
    if (hhas) insert5(t0, t1, t2, t3, t4, hv);
    #pragma unroll
    for (int q = 0; q < NQA; ++q) insert5x4(t0, t1, t2, t3, t4, pa[q]);

    block_top5(t0, t1, t2, t3, t4, red, s5a, tid);   // also fences s_cnt init
    const float th0 = s5a[4];      // provable lower bound on the final threshold

    // ---- Phase B: stream rest 4-deep, write zeros, bank rare candidates ----
    const f32x4 z4 = {0.0f, 0.0f, 0.0f, 0.0f};
    int i = NVA + tid;
    for (; i + 3 * BS < nvec; i += 4 * BS) {
        f32x4 a0 = xv[i];                 // 4 loads issued back-to-back
        f32x4 a1 = xv[i + BS];
        f32x4 a2 = xv[i + 2 * BS];
        f32x4 a3 = xv[i + 3 * BS];
        ov[i]          = z4;              // independent stores
        ov[i + BS]     = z4;
        ov[i + 2 * BS] = z4;
        ov[i + 3 * BS] = z4;
        const int eb = head + (i << 2);
        scan4(a0, eb,            th0, &s_cnt, s_idx, s_val);
        scan4(a1, eb + 4 * BS,   th0, &s_cnt, s_idx, s_val);
        scan4(a2, eb + 8 * BS,   th0, &s_cnt, s_idx, s_val);
        scan4(a3, eb + 12 * BS,  th0, &s_cnt, s_idx, s_val);
    }
    for (; i < nvec; i += BS) {
        f32x4 a = xv[i];
        ov[i] = z4;
        scan4(a, head + (i << 2), th0, &s_cnt, s_idx, s_val);
    }
    for (int s = tail + tid; s < NC; s += BS) {      // <=3 trailing scalars
        float v = xr[s];
        outr[s] = 0.0f;
        if (v >= th0) { int sl = atomicAdd(&s_cnt, 1); if (sl < CAP) { s_idx[sl] = s; s_val[sl] = v; } }
    }
    __syncthreads();

    const int cnt_raw = s_cnt;
    const int cnt = cnt_raw < CAP ? cnt_raw : CAP;
    const bool ovf = cnt_raw > CAP;

    if (!ovf) {
        // ---- Final threshold = top-5 of (phase-A top-5  U  candidates) ----
        float c0 = -INFINITY, c1 = -INFINITY, c2 = -INFINITY, c3 = -INFINITY, c4 = -INFINITY;
        for (int i2 = tid; i2 < cnt; i2 += BS) insert5(c0, c1, c2, c3, c4, s_val[i2]);
        block_top5(c0, c1, c2, c3, c4, red, s5c, tid);
        float m0 = s5c[0], m1 = s5c[1], m2 = s5c[2], m3 = s5c[3], m4 = s5c[4];
        merge5(m0, m1, m2, m3, m4, s5a[0], s5a[1], s5a[2], s5a[3], s5a[4]);
        const float th = m4;

        // ---- Write prefix straight from registers (no re-read) ----
        if (hhas) outr[tid] = hv >= th ? hv : 0.0f;
        #pragma unroll
        for (int q = 0; q < NQA; ++q) {
            f32x4 a = pa[q];
            f32x4 o;
            o.x = a.x >= th ? a.x : 0.0f;
            o.y = a.y >= th ? a.y : 0.0f;
            o.z = a.z >= th ? a.z : 0.0f;
            o.w = a.w >= th ? a.w : 0.0f;
            ov[tid + q * BS] = o;
        }
        // ---- Candidate fixup (scattered, ~56 stores/row) ----
        for (int i2 = tid; i2 < cnt; i2 += BS) {
            if (s_val[i2] >= th) outr[s_idx[i2]] = s_val[i2];
        }
    } else {
        // ---- Fallback (unreachable for random data): exact 2-pass recompute ----
        float f0 = -INFINITY, f1 = -INFINITY, f2 = -INFINITY, f3 = -INFINITY, f4 = -INFINITY;
        if (hhas) insert5(f0, f1, f2, f3, f4, hv);
        for (int i2 = tid; i2 < nvec; i2 += BS) {
            f32x4 a = xv[i2];
            insert5x4(f0, f1, f2, f3, f4, a);
        }
        for (int s = tail + tid; s < NC; s += BS) insert5(f0, f1, f2, f3, f4, xr[s]);
        block_top5(f0, f1, f2, f3, f4, red, s5c, tid);
        const float th = s5c[4];
        if (hhas) outr[tid] = hv >= th ? hv : 0.0f;
        for (int i2 = tid; i2 < nvec; i2 += BS) {
            f32x4 a = xv[i2];
            f32x4 o;
            o.x = a.x >= th ? a.x : 0.0f;
            o.y = a.y >= th ? a.y : 0.0f;
            o.z = a.z >= th ? a.z : 0.0f;
            o.w = a.w >= th ? a.w : 0.0f;
            ov[i2] = o;
        }
        for (int s = tail + tid; s < NC; s += BS) {
            float v = xr[s];
            outr[s] = v >= th ? v : 0.0f;
        }
    }
}

extern "C" void kernel_launch(void* const* d_in, const int* in_sizes, int n_in,
                              void* d_out, int out_size, void* d_ws, size_t ws_size,
                              hipStream_t stream) {
    (void)in_sizes; (void)n_in; (void)d_ws; (void)ws_size; (void)out_size;
    const float* x = (const float*)d_in[0];
    float* out = (float*)d_out;
    // k is fixed at 5 by the reference setup (d_in[1] holds it); kernel is specialized.
    topk5_thresh_kernel<<<NROWS, BS, 0, stream>>>(x, out);
}